// Round 9
// baseline (3024.155 us; speedup 1.0000x reference)
//
#include <hip/hip_runtime.h>
#include <hip/hip_fp16.h>

#define N_NODES 100000
#define EDGES   1600000
#define D       128
#define BN_EPS  1e-5f
#define TM      64                        // rows per GEMM block
#define NB      ((N_NODES + 255) >> 8)    // 391 dst buckets (256 nodes each)
#define NG      (2 * NB)                  // 782 gather half-buckets (128 nodes)
#define L1E     16                        // slots per thread in partition pass
#define L1TILE  (256 * L1E)               // 4096 slots per tile

typedef __attribute__((ext_vector_type(8))) short short8;
typedef __attribute__((ext_vector_type(4))) float f32x4;

__device__ __forceinline__ unsigned short bf_hi(float f) {
    unsigned u = __float_as_uint(f);
    unsigned t = u + 0x7FFF + ((u >> 16) & 1);
    return (unsigned short)(t >> 16);
}
__device__ __forceinline__ float bf_val(unsigned short h) {
    return __uint_as_float(((unsigned)h) << 16);
}

// ---------------------------------------------------------------------------
// K0: convert x -> fp16 mirror (in d_out scratch); zero stats(512f)+bsum(512i)
// ---------------------------------------------------------------------------
__global__ void convert_zero(const float* __restrict__ x, __half* __restrict__ xh,
                             int* __restrict__ zbase) {
    int gid = blockIdx.x * blockDim.x + threadIdx.x;
    if (gid < 1024) zbase[gid] = 0;
    const int n4 = N_NODES * (D / 4);
    if (gid < n4) {
        float4 v = ((const float4*)x)[gid];
        __half2 h0 = __float22half2_rn(make_float2(v.x, v.y));
        __half2 h1 = __float22half2_rn(make_float2(v.z, v.w));
        ((__half2*)xh)[(long long)gid * 2 + 0] = h0;
        ((__half2*)xh)[(long long)gid * 2 + 1] = h1;
    }
}

// ---------------------------------------------------------------------------
// K1: bucket-level histogram (LDS counters, 1 atomic per tile-bucket)
// ---------------------------------------------------------------------------
__launch_bounds__(256)
__global__ void bucket_count(const int* __restrict__ ei, int* __restrict__ bsum) {
    __shared__ int cnt[NB];
    const int tid = threadIdx.x;
    for (int i = tid; i < NB; i += 256) cnt[i] = 0;
    __syncthreads();
    const int t0 = blockIdx.x * L1TILE + tid;
#pragma unroll
    for (int j = 0; j < L1E; ++j) {
        int t = t0 + j * 256;
        if (t < 2 * EDGES) {
            int pt = (t < EDGES) ? t + EDGES : t - EDGES;
            atomicAdd(&cnt[ei[pt] >> 8], 1);
        }
    }
    __syncthreads();
    for (int i = tid; i < NB; i += 256) {
        int c = cnt[i];
        if (c) atomicAdd(&bsum[i], c);
    }
}

// ---------------------------------------------------------------------------
// K2: exclusive scan of 391 bucket sums -> bbase (NB+1), seed gcur
// ---------------------------------------------------------------------------
__global__ void scan_bsums(const int* __restrict__ bsum, int* __restrict__ bbase,
                           int* __restrict__ gcur) {
    __shared__ int s[512];
    const int t = threadIdx.x;
    s[t] = (t < NB) ? bsum[t] : 0;
    __syncthreads();
    for (int d = 1; d < 512; d <<= 1) {
        int u = (t >= d) ? s[t - d] : 0;
        __syncthreads();
        s[t] += u;
        __syncthreads();
    }
    if (t < NB) {
        int e = (t > 0) ? s[t - 1] : 0;
        bbase[t] = e;
        gcur[t] = e;
    }
    if (t == 0) bbase[NB] = 2 * EDGES;
}

// ---------------------------------------------------------------------------
// K2d: split W1/W2 into bf16 hi/lo
// ---------------------------------------------------------------------------
__global__ void split_w(const float* __restrict__ W1, const float* __restrict__ W2,
                        unsigned short* __restrict__ w1h, unsigned short* __restrict__ w1l,
                        unsigned short* __restrict__ w2h, unsigned short* __restrict__ w2l) {
    int i = blockIdx.x * blockDim.x + threadIdx.x;
    if (i < 16384) {
        float f = W1[i];
        unsigned short h = bf_hi(f);
        w1h[i] = h;
        w1l[i] = bf_hi(f - bf_val(h));
    } else if (i < 32768) {
        int j = i - 16384;
        float f = W2[j];
        unsigned short h = bf_hi(f);
        w2h[j] = h;
        w2l[j] = bf_hi(f - bf_val(h));
    }
}

// ---------------------------------------------------------------------------
// K3a: partition into 391 dst buckets; pack pair as (local_node<<17)|src
// ---------------------------------------------------------------------------
__launch_bounds__(256)
__global__ void partition_pairs(const int* __restrict__ ei, int* __restrict__ gcur,
                                int* __restrict__ pairs1) {
    __shared__ int cnt[NB];
    __shared__ int cbase[NB];
    const int tid = threadIdx.x;
    for (int i = tid; i < NB; i += 256) cnt[i] = 0;
    __syncthreads();

    int bb[L1E], rr[L1E], pk[L1E];
    const int t0 = blockIdx.x * L1TILE + tid;
#pragma unroll
    for (int j = 0; j < L1E; ++j) {
        int t = t0 + j * 256;
        bb[j] = -1;
        if (t < 2 * EDGES) {
            int vl = ei[t];
            int pt = (t < EDGES) ? t + EDGES : t - EDGES;
            int nd = ei[pt];
            bb[j] = nd >> 8;
            pk[j] = ((nd & 255) << 17) | vl;
            rr[j] = atomicAdd(&cnt[bb[j]], 1);
        }
    }
    __syncthreads();
    for (int i = tid; i < NB; i += 256) {
        int c = cnt[i];
        cbase[i] = c ? atomicAdd(&gcur[i], c) : 0;
    }
    __syncthreads();
#pragma unroll
    for (int j = 0; j < L1E; ++j) {
        if (bb[j] >= 0) pairs1[cbase[bb[j]] + rr[j]] = pk[j];
    }
}

// ---------------------------------------------------------------------------
// K3b: per dst-bucket LDS counting sort by (dst-half, src>>8) -> pairs2,
// and emit half-bucket bases bbase2[NG+1]
// ---------------------------------------------------------------------------
__launch_bounds__(512)
__global__ void sort_pairs(const int* __restrict__ pairs1, const int* __restrict__ bbase,
                           int* __restrict__ pairs2, int* __restrict__ bbase2) {
    __shared__ int s[1024];
    __shared__ int cur[NG];
    const int b = blockIdx.x, tid = threadIdx.x;
    const int s0 = bbase[b], s1 = bbase[b + 1];
    s[tid] = 0; s[tid + 512] = 0;
    __syncthreads();
    for (int i = s0 + tid; i < s1; i += 512) {
        int p = pairs1[i];
        int cell = ((p >> 24) & 1) * NB + ((p & 0x1FFFF) >> 8);
        atomicAdd(&s[cell], 1);
    }
    __syncthreads();
    int o0 = s[tid], o1 = s[tid + 512];
    for (int d = 1; d < 1024; d <<= 1) {          // inclusive Hillis-Steele
        int v0 = (tid >= d) ? s[tid - d] : 0;
        int v1 = (tid + 512 >= d) ? s[tid + 512 - d] : 0;
        __syncthreads();
        s[tid] += v0; s[tid + 512] += v1;
        __syncthreads();
    }
    if (tid < NG) cur[tid] = s0 + s[tid] - o0;    // exclusive scan + base
    if (tid + 512 < NG) cur[tid + 512] = s0 + s[tid + 512] - o1;
    if (tid == 0) {
        bbase2[2 * b]     = s0;
        bbase2[2 * b + 1] = s0 + s[NB - 1];       // half0 total
        if (b == NB - 1) bbase2[NG] = 2 * EDGES;
    }
    __syncthreads();
    for (int i = s0 + tid; i < s1; i += 512) {
        int p = pairs1[i];
        int cell = ((p >> 24) & 1) * NB + ((p & 0x1FFFF) >> 8);
        int r = atomicAdd(&cur[cell], 1);
        pairs2[r] = p;
    }
}

// ---------------------------------------------------------------------------
// K4: gather_scatter: block = 128-node half-bucket, 64KB LDS fp32 accum;
// pairs processed in ascending-src order -> L2-resident sliding window.
// accum col layout: c -> (c&1)*64 + (c>>1)  (conflict-free ds_add)
// ---------------------------------------------------------------------------
__launch_bounds__(512)
__global__ void gather_scatter(const float* __restrict__ x, const __half* __restrict__ xh,
                               const int* __restrict__ pairs2, const int* __restrict__ bbase2,
                               const float* __restrict__ eps_p,
                               unsigned* __restrict__ hh, unsigned* __restrict__ hl) {
    __shared__ float acc[128][128];               // 64 KB
    const int g = blockIdx.x;
    const int tid = threadIdx.x;
    const int lane = tid & 63, wv = tid >> 6;     // 8 waves
    const int n0 = g << 7;
    const int s0 = bbase2[g], s1 = bbase2[g + 1];
#pragma unroll
    for (int i = tid; i < 128 * 128 / 4; i += 512)
        ((float4*)acc)[i] = make_float4(0.f, 0.f, 0.f, 0.f);
    __syncthreads();
    const __half2* xp = (const __half2*)xh;
    for (int i0 = s0 + wv * 8; i0 < s1; i0 += 64) {
        int pk[8]; __half2 hv[8];
#pragma unroll
        for (int j = 0; j < 8; ++j) {
            int idx = i0 + j;
            pk[j] = (idx < s1) ? pairs2[idx] : -1;
        }
#pragma unroll
        for (int j = 0; j < 8; ++j)
            if (pk[j] >= 0) hv[j] = xp[(long long)(pk[j] & 0x1FFFF) * 64 + lane];
#pragma unroll
        for (int j = 0; j < 8; ++j)
            if (pk[j] >= 0) {
                int r = ((unsigned)pk[j] >> 17) & 127;
                float2 f = __half22float2(hv[j]);
                atomicAdd(&acc[r][lane],      f.x);   // col 2*lane
                atomicAdd(&acc[r][64 + lane], f.y);   // col 2*lane+1
            }
    }
    __syncthreads();
    const float sc = 2.0f + eps_p[0];
#pragma unroll
    for (int rr = 0; rr < 16; ++rr) {
        int r = wv * 16 + rr;
        int n = n0 + r;
        if (n < N_NODES) {
            float2 xs = ((const float2*)x)[(long long)n * 64 + lane];
            float ox = fmaf(sc, xs.x, acc[r][lane]);
            float oy = fmaf(sc, xs.y, acc[r][64 + lane]);
            unsigned short hx = bf_hi(ox), hy = bf_hi(oy);
            unsigned short lx = bf_hi(ox - bf_val(hx)), ly = bf_hi(oy - bf_val(hy));
            hh[(long long)n * 64 + lane] = (unsigned)hx | ((unsigned)hy << 16);
            hl[(long long)n * 64 + lane] = (unsigned)lx | ((unsigned)ly << 16);
        }
    }
}

// ---------------------------------------------------------------------------
// K5: h1 = h_pre @ W1^T + b1 (MFMA split-bf16, fp32-accurate) + BN stats
// ---------------------------------------------------------------------------
__launch_bounds__(256)
__global__ void gemm1_mfma(const unsigned short* __restrict__ hh,
                           const unsigned short* __restrict__ hl,
                           const unsigned short* __restrict__ w1h,
                           const unsigned short* __restrict__ w1l,
                           const float* __restrict__ b1, float* __restrict__ h1,
                           float* __restrict__ stats) {
    __shared__ unsigned short sH[TM][136];
    __shared__ unsigned short sL[TM][136];
    __shared__ float sPart[2][4][128];
    const int tid = threadIdx.x;
    const int wv  = tid >> 6;
    const int ln  = tid & 63;
    const int lc  = ln & 15;
    const int qd  = ln >> 4;
    const int row0 = blockIdx.x * TM;

#pragma unroll
    for (int i = 0; i < 4; ++i) {
        int f = tid + 256 * i;
        int r = f >> 4, c8 = f & 15;
        int gr = row0 + r;
        uint4 vh = make_uint4(0, 0, 0, 0), vl = make_uint4(0, 0, 0, 0);
        if (gr < N_NODES) {
            vh = *(const uint4*)(hh + (long long)gr * D + c8 * 8);
            vl = *(const uint4*)(hl + (long long)gr * D + c8 * 8);
        }
        *(uint4*)&sH[r][c8 * 8] = vh;
        *(uint4*)&sL[r][c8 * 8] = vl;
    }
    __syncthreads();

    f32x4 acc[8];
#pragma unroll
    for (int t = 0; t < 8; ++t) acc[t] = (f32x4){0.f, 0.f, 0.f, 0.f};

    const int arow = wv * 16 + lc;
#pragma unroll
    for (int kk = 0; kk < 4; ++kk) {
        short8 ah = *(const short8*)&sH[arow][kk * 32 + qd * 8];
        short8 al = *(const short8*)&sL[arow][kk * 32 + qd * 8];
#pragma unroll
        for (int t = 0; t < 8; ++t) {
            const int woff = (t * 16 + lc) * D + kk * 32 + qd * 8;
            short8 bh = *(const short8*)(w1h + woff);
            short8 bl = *(const short8*)(w1l + woff);
            acc[t] = __builtin_amdgcn_mfma_f32_16x16x32_bf16(ah, bh, acc[t], 0, 0, 0);
            acc[t] = __builtin_amdgcn_mfma_f32_16x16x32_bf16(al, bh, acc[t], 0, 0, 0);
            acc[t] = __builtin_amdgcn_mfma_f32_16x16x32_bf16(ah, bl, acc[t], 0, 0, 0);
        }
    }

    float psum[8], psq[8];
#pragma unroll
    for (int t = 0; t < 8; ++t) {
        int col = t * 16 + lc;
        float bb = b1[col];
        float s = 0.f, q = 0.f;
#pragma unroll
        for (int r = 0; r < 4; ++r) {
            int grow = row0 + wv * 16 + qd * 4 + r;
            if (grow < N_NODES) {
                float o = acc[t][r] + bb;
                h1[(long long)grow * D + col] = o;
                s += o;
                q += o * o;
            }
        }
        psum[t] = s; psq[t] = q;
    }
#pragma unroll
    for (int t = 0; t < 8; ++t) {
        float s = psum[t], q = psq[t];
        s += __shfl_xor(s, 16); s += __shfl_xor(s, 32);
        q += __shfl_xor(q, 16); q += __shfl_xor(q, 32);
        if (qd == 0) { sPart[0][wv][t * 16 + lc] = s; sPart[1][wv][t * 16 + lc] = q; }
    }
    __syncthreads();
    if (tid < 128) {
        float s = sPart[0][0][tid] + sPart[0][1][tid] + sPart[0][2][tid] + sPart[0][3][tid];
        float q = sPart[1][0][tid] + sPart[1][1][tid] + sPart[1][2][tid] + sPart[1][3][tid];
        atomicAdd(&stats[tid], s);
        atomicAdd(&stats[128 + tid], q);
    }
}

// ---------------------------------------------------------------------------
// K6: out = relu(bn(h1)) @ W2^T + b2  (MFMA split-bf16), in-place on d_out
// ---------------------------------------------------------------------------
__launch_bounds__(256)
__global__ void gemm2_mfma(float* __restrict__ h1out,
                           const unsigned short* __restrict__ w2h,
                           const unsigned short* __restrict__ w2l,
                           const float* __restrict__ b2, const float* __restrict__ stats,
                           const float* __restrict__ gamma, const float* __restrict__ beta) {
    __shared__ unsigned short sH[TM][136];
    __shared__ unsigned short sL[TM][136];
    __shared__ float sScale[128];
    __shared__ float sShift[128];
    const int tid = threadIdx.x;
    const int wv  = tid >> 6;
    const int ln  = tid & 63;
    const int lc  = ln & 15;
    const int qd  = ln >> 4;
    const int row0 = blockIdx.x * TM;

    if (tid < 128) {
        float mean = stats[tid] * (1.0f / N_NODES);
        float var  = fmaxf(stats[128 + tid] * (1.0f / N_NODES) - mean * mean, 0.0f);
        float s    = gamma[tid] * rsqrtf(var + BN_EPS);
        sScale[tid] = s;
        sShift[tid] = beta[tid] - mean * s;
    }
    __syncthreads();

#pragma unroll
    for (int i = 0; i < 8; ++i) {
        int f = tid + 256 * i;
        int r = f >> 5, c4 = f & 31;
        int gr = row0 + r;
        float4 v = make_float4(0.f, 0.f, 0.f, 0.f);
        if (gr < N_NODES) {
            v = *(const float4*)(h1out + (long long)gr * D + c4 * 4);
            float4 sc = *(const float4*)&sScale[c4 * 4];
            float4 sh = *(const float4*)&sShift[c4 * 4];
            v.x = fmaxf(0.f, fmaf(v.x, sc.x, sh.x));
            v.y = fmaxf(0.f, fmaf(v.y, sc.y, sh.y));
            v.z = fmaxf(0.f, fmaf(v.z, sc.z, sh.z));
            v.w = fmaxf(0.f, fmaf(v.w, sc.w, sh.w));
        }
        unsigned short h0 = bf_hi(v.x), h1b = bf_hi(v.y), h2 = bf_hi(v.z), h3 = bf_hi(v.w);
        unsigned short l0 = bf_hi(v.x - bf_val(h0)), l1 = bf_hi(v.y - bf_val(h1b));
        unsigned short l2 = bf_hi(v.z - bf_val(h2)), l3 = bf_hi(v.w - bf_val(h3));
        *(uint2*)&sH[r][c4 * 4] = make_uint2((unsigned)h0 | ((unsigned)h1b << 16),
                                             (unsigned)h2 | ((unsigned)h3 << 16));
        *(uint2*)&sL[r][c4 * 4] = make_uint2((unsigned)l0 | ((unsigned)l1 << 16),
                                             (unsigned)l2 | ((unsigned)l3 << 16));
    }
    __syncthreads();

    f32x4 acc[8];
#pragma unroll
    for (int t = 0; t < 8; ++t) acc[t] = (f32x4){0.f, 0.f, 0.f, 0.f};

    const int arow = wv * 16 + lc;
#pragma unroll
    for (int kk = 0; kk < 4; ++kk) {
        short8 ah = *(const short8*)&sH[arow][kk * 32 + qd * 8];
        short8 al = *(const short8*)&sL[arow][kk * 32 + qd * 8];
#pragma unroll
        for (int t = 0; t < 8; ++t) {
            const int woff = (t * 16 + lc) * D + kk * 32 + qd * 8;
            short8 bh = *(const short8*)(w2h + woff);
            short8 bl = *(const short8*)(w2l + woff);
            acc[t] = __builtin_amdgcn_mfma_f32_16x16x32_bf16(ah, bh, acc[t], 0, 0, 0);
            acc[t] = __builtin_amdgcn_mfma_f32_16x16x32_bf16(al, bh, acc[t], 0, 0, 0);
            acc[t] = __builtin_amdgcn_mfma_f32_16x16x32_bf16(ah, bl, acc[t], 0, 0, 0);
        }
    }

#pragma unroll
    for (int t = 0; t < 8; ++t) {
        int col = t * 16 + lc;
        float bb = b2[col];
#pragma unroll
        for (int r = 0; r < 4; ++r) {
            int grow = row0 + wv * 16 + qd * 4 + r;
            if (grow < N_NODES) {
                h1out[(long long)grow * D + col] = acc[t][r] + bb;
            }
        }
    }
}

// ---------------------------------------------------------------------------
extern "C" void kernel_launch(void* const* d_in, const int* in_sizes, int n_in,
                              void* d_out, int out_size, void* d_ws, size_t ws_size,
                              hipStream_t stream) {
    const float* x     = (const float*)d_in[0];
    const int*   ei    = (const int*)d_in[1];
    const float* eps_p = (const float*)d_in[2];
    const float* W1    = (const float*)d_in[3];
    const float* b1    = (const float*)d_in[4];
    const float* gamma = (const float*)d_in[5];
    const float* beta  = (const float*)d_in[6];
    const float* W2    = (const float*)d_in[7];
    const float* b2    = (const float*)d_in[8];

    // workspace layout (~64.2 MB)
    unsigned int* hh  = (unsigned int*)d_ws;                  // N*64 uints: hpre hi
    unsigned int* hl  = hh + (long long)N_NODES * 64;         // hpre lo
    float* stats  = (float*)(hl + (long long)N_NODES * 64);   // 512 floats
    int*   bsum   = (int*)(stats + 512);                      // 512 ints (zeroed w/ stats)
    int*   bbase  = bsum + 512;                               // NB+1 ints
    int*   gcur   = bbase + 512;                              // NB ints
    int*   bbase2 = gcur + 512;                               // NG+1 ints
    unsigned short* w1h = (unsigned short*)(bbase2 + 1024);
    unsigned short* w1l = w1h + 16384;
    unsigned short* w2h = w1l + 16384;
    unsigned short* w2l = w2h + 16384;
    int*   pairs2 = (int*)(w2l + 16384);                      // 2E ints = 12.8 MB

    float* out    = (float*)d_out;                            // h1 scratch + final out
    __half* xh    = (__half*)d_out;                           // fp16 mirror: d_out[0:25.6MB]
    int*   pairs1 = (int*)(out + (long long)N_NODES * (D / 2)); // d_out[25.6:38.4MB]

    {   // K0: fp16 convert + zero stats/bsum
        int grid = (N_NODES * (D / 4) + 255) / 256;
        convert_zero<<<grid, 256, 0, stream>>>(x, xh, (int*)stats);
    }
    {   // K1: bucket histogram
        int grid = (2 * EDGES + L1TILE - 1) / L1TILE;
        bucket_count<<<grid, 256, 0, stream>>>(ei, bsum);
    }
    {   // K2: scan bucket sums -> bbase, gcur
        scan_bsums<<<1, 512, 0, stream>>>(bsum, bbase, gcur);
    }
    {   // K2d: split W1/W2 -> bf16 hi/lo
        split_w<<<128, 256, 0, stream>>>(W1, W2, w1h, w1l, w2h, w2l);
    }
    {   // K3a: dst-bucket partition (packed pairs)
        int grid = (2 * EDGES + L1TILE - 1) / L1TILE;
        partition_pairs<<<grid, 256, 0, stream>>>(ei, gcur, pairs1);
    }
    {   // K3b: per-bucket counting sort by (half, src-bucket) -> pairs2, bbase2
        sort_pairs<<<NB, 512, 0, stream>>>(pairs1, bbase, pairs2, bbase2);
    }
    {   // K4: src-ordered scatter-gather into LDS accumulators -> hh/hl
        gather_scatter<<<NG, 512, 0, stream>>>(x, xh, pairs2, bbase2, eps_p, hh, hl);
    }
    {   // K5: MFMA GEMM1 + BN stats (h1 -> d_out)
        int grid = (N_NODES + TM - 1) / TM;
        gemm1_mfma<<<grid, 256, 0, stream>>>((const unsigned short*)hh, (const unsigned short*)hl,
                                             w1h, w1l, b1, out, stats);
    }
    {   // K6: BN finalize + ReLU + MFMA GEMM2, in-place on d_out
        int grid = (N_NODES + TM - 1) / TM;
        gemm2_mfma<<<grid, 256, 0, stream>>>(out, w2h, w2l, b2, stats, gamma, beta);
    }
}

// Round 10
// 566.681 us; speedup vs baseline: 5.3366x; 5.3366x over previous
//
#include <hip/hip_runtime.h>
#include <hip/hip_fp16.h>

#define N_NODES 100000
#define EDGES   1600000
#define D       128
#define BN_EPS  1e-5f
#define TM      64                        // rows per GEMM block
#define NB      ((N_NODES + 255) >> 8)    // 391 dst buckets (256 nodes each)
#define NG      (2 * NB)                  // 782 gather half-buckets (128 nodes)
#define L1E     16                        // slots per thread in partition pass
#define L1TILE  (256 * L1E)               // 4096 slots per tile
#define FXS     1048576.0f                // 2^20 fixed-point scale
#define FXI     (1.0f / 1048576.0f)

typedef __attribute__((ext_vector_type(8))) short short8;
typedef __attribute__((ext_vector_type(4))) float f32x4;

__device__ __forceinline__ unsigned short bf_hi(float f) {
    unsigned u = __float_as_uint(f);
    unsigned t = u + 0x7FFF + ((u >> 16) & 1);
    return (unsigned short)(t >> 16);
}
__device__ __forceinline__ float bf_val(unsigned short h) {
    return __uint_as_float(((unsigned)h) << 16);
}

// ---------------------------------------------------------------------------
// K0: convert x -> fp16 mirror (in d_out scratch); zero stats(512f)+bsum(512i)
// ---------------------------------------------------------------------------
__global__ void convert_zero(const float* __restrict__ x, __half* __restrict__ xh,
                             int* __restrict__ zbase) {
    int gid = blockIdx.x * blockDim.x + threadIdx.x;
    if (gid < 1024) zbase[gid] = 0;
    const int n4 = N_NODES * (D / 4);
    if (gid < n4) {
        float4 v = ((const float4*)x)[gid];
        __half2 h0 = __float22half2_rn(make_float2(v.x, v.y));
        __half2 h1 = __float22half2_rn(make_float2(v.z, v.w));
        ((__half2*)xh)[(long long)gid * 2 + 0] = h0;
        ((__half2*)xh)[(long long)gid * 2 + 1] = h1;
    }
}

// ---------------------------------------------------------------------------
// K1: bucket-level histogram (LDS counters, 1 atomic per tile-bucket)
// ---------------------------------------------------------------------------
__launch_bounds__(256)
__global__ void bucket_count(const int* __restrict__ ei, int* __restrict__ bsum) {
    __shared__ int cnt[NB];
    const int tid = threadIdx.x;
    for (int i = tid; i < NB; i += 256) cnt[i] = 0;
    __syncthreads();
    const int t0 = blockIdx.x * L1TILE + tid;
#pragma unroll
    for (int j = 0; j < L1E; ++j) {
        int t = t0 + j * 256;
        if (t < 2 * EDGES) {
            int pt = (t < EDGES) ? t + EDGES : t - EDGES;
            atomicAdd(&cnt[ei[pt] >> 8], 1);
        }
    }
    __syncthreads();
    for (int i = tid; i < NB; i += 256) {
        int c = cnt[i];
        if (c) atomicAdd(&bsum[i], c);
    }
}

// ---------------------------------------------------------------------------
// K2: exclusive scan of 391 bucket sums -> bbase (NB+1), seed gcur
// ---------------------------------------------------------------------------
__global__ void scan_bsums(const int* __restrict__ bsum, int* __restrict__ bbase,
                           int* __restrict__ gcur) {
    __shared__ int s[512];
    const int t = threadIdx.x;
    s[t] = (t < NB) ? bsum[t] : 0;
    __syncthreads();
    for (int d = 1; d < 512; d <<= 1) {
        int u = (t >= d) ? s[t - d] : 0;
        __syncthreads();
        s[t] += u;
        __syncthreads();
    }
    if (t < NB) {
        int e = (t > 0) ? s[t - 1] : 0;
        bbase[t] = e;
        gcur[t] = e;
    }
    if (t == 0) bbase[NB] = 2 * EDGES;
}

// ---------------------------------------------------------------------------
// K2d: split W1/W2 into bf16 hi/lo
// ---------------------------------------------------------------------------
__global__ void split_w(const float* __restrict__ W1, const float* __restrict__ W2,
                        unsigned short* __restrict__ w1h, unsigned short* __restrict__ w1l,
                        unsigned short* __restrict__ w2h, unsigned short* __restrict__ w2l) {
    int i = blockIdx.x * blockDim.x + threadIdx.x;
    if (i < 16384) {
        float f = W1[i];
        unsigned short h = bf_hi(f);
        w1h[i] = h;
        w1l[i] = bf_hi(f - bf_val(h));
    } else if (i < 32768) {
        int j = i - 16384;
        float f = W2[j];
        unsigned short h = bf_hi(f);
        w2h[j] = h;
        w2l[j] = bf_hi(f - bf_val(h));
    }
}

// ---------------------------------------------------------------------------
// K3a: partition into 391 dst buckets; pack pair as (local_node<<17)|src
// ---------------------------------------------------------------------------
__launch_bounds__(256)
__global__ void partition_pairs(const int* __restrict__ ei, int* __restrict__ gcur,
                                int* __restrict__ pairs1) {
    __shared__ int cnt[NB];
    __shared__ int cbase[NB];
    const int tid = threadIdx.x;
    for (int i = tid; i < NB; i += 256) cnt[i] = 0;
    __syncthreads();

    int bb[L1E], rr[L1E], pk[L1E];
    const int t0 = blockIdx.x * L1TILE + tid;
#pragma unroll
    for (int j = 0; j < L1E; ++j) {
        int t = t0 + j * 256;
        bb[j] = -1;
        if (t < 2 * EDGES) {
            int vl = ei[t];
            int pt = (t < EDGES) ? t + EDGES : t - EDGES;
            int nd = ei[pt];
            bb[j] = nd >> 8;
            pk[j] = ((nd & 255) << 17) | vl;
            rr[j] = atomicAdd(&cnt[bb[j]], 1);
        }
    }
    __syncthreads();
    for (int i = tid; i < NB; i += 256) {
        int c = cnt[i];
        cbase[i] = c ? atomicAdd(&gcur[i], c) : 0;
    }
    __syncthreads();
#pragma unroll
    for (int j = 0; j < L1E; ++j) {
        if (bb[j] >= 0) pairs1[cbase[bb[j]] + rr[j]] = pk[j];
    }
}

// ---------------------------------------------------------------------------
// K3b: per dst-bucket LDS counting sort by (dst-half, src>>8) -> pairs2,
// and emit half-bucket bases bbase2[NG+1]
// ---------------------------------------------------------------------------
__launch_bounds__(512)
__global__ void sort_pairs(const int* __restrict__ pairs1, const int* __restrict__ bbase,
                           int* __restrict__ pairs2, int* __restrict__ bbase2) {
    __shared__ int s[1024];
    __shared__ int cur[NG];
    const int b = blockIdx.x, tid = threadIdx.x;
    const int s0 = bbase[b], s1 = bbase[b + 1];
    s[tid] = 0; s[tid + 512] = 0;
    __syncthreads();
    for (int i = s0 + tid; i < s1; i += 512) {
        int p = pairs1[i];
        int cell = ((p >> 24) & 1) * NB + ((p & 0x1FFFF) >> 8);
        atomicAdd(&s[cell], 1);
    }
    __syncthreads();
    int o0 = s[tid], o1 = s[tid + 512];
    for (int d = 1; d < 1024; d <<= 1) {          // inclusive Hillis-Steele
        int v0 = (tid >= d) ? s[tid - d] : 0;
        int v1 = (tid + 512 >= d) ? s[tid + 512 - d] : 0;
        __syncthreads();
        s[tid] += v0; s[tid + 512] += v1;
        __syncthreads();
    }
    if (tid < NG) cur[tid] = s0 + s[tid] - o0;    // exclusive scan + base
    if (tid + 512 < NG) cur[tid + 512] = s0 + s[tid + 512] - o1;
    if (tid == 0) {
        bbase2[2 * b]     = s0;
        bbase2[2 * b + 1] = s0 + s[NB - 1];       // half0 total
        if (b == NB - 1) bbase2[NG] = 2 * EDGES;
    }
    __syncthreads();
    for (int i = s0 + tid; i < s1; i += 512) {
        int p = pairs1[i];
        int cell = ((p >> 24) & 1) * NB + ((p & 0x1FFFF) >> 8);
        int r = atomicAdd(&cur[cell], 1);
        pairs2[r] = p;
    }
}

// ---------------------------------------------------------------------------
// K4: gather_scatter with FIXED-POINT int LDS accumulation (native ds_add_u32;
// R9's float atomicAdd compiled to a CAS retry loop -> 21x regression).
// block = 128-node half-bucket; 64KB int accum; sum exact in 2^-20 units.
// ---------------------------------------------------------------------------
__launch_bounds__(512)
__global__ void gather_scatter(const float* __restrict__ x, const __half* __restrict__ xh,
                               const int* __restrict__ pairs2, const int* __restrict__ bbase2,
                               const float* __restrict__ eps_p,
                               unsigned* __restrict__ hh, unsigned* __restrict__ hl) {
    __shared__ int acc[128][128];                 // 64 KB fixed-point
    const int g = blockIdx.x;
    const int tid = threadIdx.x;
    const int lane = tid & 63, wv = tid >> 6;     // 8 waves
    const int n0 = g << 7;
    const int s0 = bbase2[g], s1 = bbase2[g + 1];
#pragma unroll
    for (int i = tid; i < 128 * 128 / 4; i += 512)
        ((int4*)acc)[i] = make_int4(0, 0, 0, 0);
    __syncthreads();
    const __half2* xp = (const __half2*)xh;
    for (int i0 = s0 + wv * 8; i0 < s1; i0 += 64) {
        int pk[8]; __half2 hv[8];
#pragma unroll
        for (int j = 0; j < 8; ++j) {
            int idx = i0 + j;
            pk[j] = (idx < s1) ? pairs2[idx] : -1;
        }
#pragma unroll
        for (int j = 0; j < 8; ++j)
            if (pk[j] >= 0) hv[j] = xp[(long long)(pk[j] & 0x1FFFF) * 64 + lane];
#pragma unroll
        for (int j = 0; j < 8; ++j)
            if (pk[j] >= 0) {
                int r = ((unsigned)pk[j] >> 17) & 127;
                float2 f = __half22float2(hv[j]);
                atomicAdd(&acc[r][lane],      __float2int_rn(f.x * FXS));
                atomicAdd(&acc[r][64 + lane], __float2int_rn(f.y * FXS));
            }
    }
    __syncthreads();
    const float sc = 2.0f + eps_p[0];
#pragma unroll
    for (int rr = 0; rr < 16; ++rr) {
        int r = wv * 16 + rr;
        int n = n0 + r;
        if (n < N_NODES) {
            float2 xs = ((const float2*)x)[(long long)n * 64 + lane];
            float ox = fmaf(sc, xs.x, (float)acc[r][lane]      * FXI);
            float oy = fmaf(sc, xs.y, (float)acc[r][64 + lane] * FXI);
            unsigned short hx = bf_hi(ox), hy = bf_hi(oy);
            unsigned short lx = bf_hi(ox - bf_val(hx)), ly = bf_hi(oy - bf_val(hy));
            hh[(long long)n * 64 + lane] = (unsigned)hx | ((unsigned)hy << 16);
            hl[(long long)n * 64 + lane] = (unsigned)lx | ((unsigned)ly << 16);
        }
    }
}

// ---------------------------------------------------------------------------
// K5: h1 = h_pre @ W1^T + b1 (MFMA split-bf16, fp32-accurate) + BN stats
// ---------------------------------------------------------------------------
__launch_bounds__(256)
__global__ void gemm1_mfma(const unsigned short* __restrict__ hh,
                           const unsigned short* __restrict__ hl,
                           const unsigned short* __restrict__ w1h,
                           const unsigned short* __restrict__ w1l,
                           const float* __restrict__ b1, float* __restrict__ h1,
                           float* __restrict__ stats) {
    __shared__ unsigned short sH[TM][136];
    __shared__ unsigned short sL[TM][136];
    __shared__ float sPart[2][4][128];
    const int tid = threadIdx.x;
    const int wv  = tid >> 6;
    const int ln  = tid & 63;
    const int lc  = ln & 15;
    const int qd  = ln >> 4;
    const int row0 = blockIdx.x * TM;

#pragma unroll
    for (int i = 0; i < 4; ++i) {
        int f = tid + 256 * i;
        int r = f >> 4, c8 = f & 15;
        int gr = row0 + r;
        uint4 vh = make_uint4(0, 0, 0, 0), vl = make_uint4(0, 0, 0, 0);
        if (gr < N_NODES) {
            vh = *(const uint4*)(hh + (long long)gr * D + c8 * 8);
            vl = *(const uint4*)(hl + (long long)gr * D + c8 * 8);
        }
        *(uint4*)&sH[r][c8 * 8] = vh;
        *(uint4*)&sL[r][c8 * 8] = vl;
    }
    __syncthreads();

    f32x4 acc[8];
#pragma unroll
    for (int t = 0; t < 8; ++t) acc[t] = (f32x4){0.f, 0.f, 0.f, 0.f};

    const int arow = wv * 16 + lc;
#pragma unroll
    for (int kk = 0; kk < 4; ++kk) {
        short8 ah = *(const short8*)&sH[arow][kk * 32 + qd * 8];
        short8 al = *(const short8*)&sL[arow][kk * 32 + qd * 8];
#pragma unroll
        for (int t = 0; t < 8; ++t) {
            const int woff = (t * 16 + lc) * D + kk * 32 + qd * 8;
            short8 bh = *(const short8*)(w1h + woff);
            short8 bl = *(const short8*)(w1l + woff);
            acc[t] = __builtin_amdgcn_mfma_f32_16x16x32_bf16(ah, bh, acc[t], 0, 0, 0);
            acc[t] = __builtin_amdgcn_mfma_f32_16x16x32_bf16(al, bh, acc[t], 0, 0, 0);
            acc[t] = __builtin_amdgcn_mfma_f32_16x16x32_bf16(ah, bl, acc[t], 0, 0, 0);
        }
    }

    float psum[8], psq[8];
#pragma unroll
    for (int t = 0; t < 8; ++t) {
        int col = t * 16 + lc;
        float bb = b1[col];
        float s = 0.f, q = 0.f;
#pragma unroll
        for (int r = 0; r < 4; ++r) {
            int grow = row0 + wv * 16 + qd * 4 + r;
            if (grow < N_NODES) {
                float o = acc[t][r] + bb;
                h1[(long long)grow * D + col] = o;
                s += o;
                q += o * o;
            }
        }
        psum[t] = s; psq[t] = q;
    }
#pragma unroll
    for (int t = 0; t < 8; ++t) {
        float s = psum[t], q = psq[t];
        s += __shfl_xor(s, 16); s += __shfl_xor(s, 32);
        q += __shfl_xor(q, 16); q += __shfl_xor(q, 32);
        if (qd == 0) { sPart[0][wv][t * 16 + lc] = s; sPart[1][wv][t * 16 + lc] = q; }
    }
    __syncthreads();
    if (tid < 128) {
        float s = sPart[0][0][tid] + sPart[0][1][tid] + sPart[0][2][tid] + sPart[0][3][tid];
        float q = sPart[1][0][tid] + sPart[1][1][tid] + sPart[1][2][tid] + sPart[1][3][tid];
        atomicAdd(&stats[tid], s);
        atomicAdd(&stats[128 + tid], q);
    }
}

// ---------------------------------------------------------------------------
// K6: out = relu(bn(h1)) @ W2^T + b2  (MFMA split-bf16), in-place on d_out
// ---------------------------------------------------------------------------
__launch_bounds__(256)
__global__ void gemm2_mfma(float* __restrict__ h1out,
                           const unsigned short* __restrict__ w2h,
                           const unsigned short* __restrict__ w2l,
                           const float* __restrict__ b2, const float* __restrict__ stats,
                           const float* __restrict__ gamma, const float* __restrict__ beta) {
    __shared__ unsigned short sH[TM][136];
    __shared__ unsigned short sL[TM][136];
    __shared__ float sScale[128];
    __shared__ float sShift[128];
    const int tid = threadIdx.x;
    const int wv  = tid >> 6;
    const int ln  = tid & 63;
    const int lc  = ln & 15;
    const int qd  = ln >> 4;
    const int row0 = blockIdx.x * TM;

    if (tid < 128) {
        float mean = stats[tid] * (1.0f / N_NODES);
        float var  = fmaxf(stats[128 + tid] * (1.0f / N_NODES) - mean * mean, 0.0f);
        float s    = gamma[tid] * rsqrtf(var + BN_EPS);
        sScale[tid] = s;
        sShift[tid] = beta[tid] - mean * s;
    }
    __syncthreads();

#pragma unroll
    for (int i = 0; i < 8; ++i) {
        int f = tid + 256 * i;
        int r = f >> 5, c4 = f & 31;
        int gr = row0 + r;
        float4 v = make_float4(0.f, 0.f, 0.f, 0.f);
        if (gr < N_NODES) {
            v = *(const float4*)(h1out + (long long)gr * D + c4 * 4);
            float4 sc = *(const float4*)&sScale[c4 * 4];
            float4 sh = *(const float4*)&sShift[c4 * 4];
            v.x = fmaxf(0.f, fmaf(v.x, sc.x, sh.x));
            v.y = fmaxf(0.f, fmaf(v.y, sc.y, sh.y));
            v.z = fmaxf(0.f, fmaf(v.z, sc.z, sh.z));
            v.w = fmaxf(0.f, fmaf(v.w, sc.w, sh.w));
        }
        unsigned short h0 = bf_hi(v.x), h1b = bf_hi(v.y), h2 = bf_hi(v.z), h3 = bf_hi(v.w);
        unsigned short l0 = bf_hi(v.x - bf_val(h0)), l1 = bf_hi(v.y - bf_val(h1b));
        unsigned short l2 = bf_hi(v.z - bf_val(h2)), l3 = bf_hi(v.w - bf_val(h3));
        *(uint2*)&sH[r][c4 * 4] = make_uint2((unsigned)h0 | ((unsigned)h1b << 16),
                                             (unsigned)h2 | ((unsigned)h3 << 16));
        *(uint2*)&sL[r][c4 * 4] = make_uint2((unsigned)l0 | ((unsigned)l1 << 16),
                                             (unsigned)l2 | ((unsigned)l3 << 16));
    }
    __syncthreads();

    f32x4 acc[8];
#pragma unroll
    for (int t = 0; t < 8; ++t) acc[t] = (f32x4){0.f, 0.f, 0.f, 0.f};

    const int arow = wv * 16 + lc;
#pragma unroll
    for (int kk = 0; kk < 4; ++kk) {
        short8 ah = *(const short8*)&sH[arow][kk * 32 + qd * 8];
        short8 al = *(const short8*)&sL[arow][kk * 32 + qd * 8];
#pragma unroll
        for (int t = 0; t < 8; ++t) {
            const int woff = (t * 16 + lc) * D + kk * 32 + qd * 8;
            short8 bh = *(const short8*)(w2h + woff);
            short8 bl = *(const short8*)(w2l + woff);
            acc[t] = __builtin_amdgcn_mfma_f32_16x16x32_bf16(ah, bh, acc[t], 0, 0, 0);
            acc[t] = __builtin_amdgcn_mfma_f32_16x16x32_bf16(al, bh, acc[t], 0, 0, 0);
            acc[t] = __builtin_amdgcn_mfma_f32_16x16x32_bf16(ah, bl, acc[t], 0, 0, 0);
        }
    }

#pragma unroll
    for (int t = 0; t < 8; ++t) {
        int col = t * 16 + lc;
        float bb = b2[col];
#pragma unroll
        for (int r = 0; r < 4; ++r) {
            int grow = row0 + wv * 16 + qd * 4 + r;
            if (grow < N_NODES) {
                h1out[(long long)grow * D + col] = acc[t][r] + bb;
            }
        }
    }
}

// ---------------------------------------------------------------------------
extern "C" void kernel_launch(void* const* d_in, const int* in_sizes, int n_in,
                              void* d_out, int out_size, void* d_ws, size_t ws_size,
                              hipStream_t stream) {
    const float* x     = (const float*)d_in[0];
    const int*   ei    = (const int*)d_in[1];
    const float* eps_p = (const float*)d_in[2];
    const float* W1    = (const float*)d_in[3];
    const float* b1    = (const float*)d_in[4];
    const float* gamma = (const float*)d_in[5];
    const float* beta  = (const float*)d_in[6];
    const float* W2    = (const float*)d_in[7];
    const float* b2    = (const float*)d_in[8];

    // workspace layout (~64.2 MB)
    unsigned int* hh  = (unsigned int*)d_ws;                  // N*64 uints: hpre hi
    unsigned int* hl  = hh + (long long)N_NODES * 64;         // hpre lo
    float* stats  = (float*)(hl + (long long)N_NODES * 64);   // 512 floats
    int*   bsum   = (int*)(stats + 512);                      // 512 ints (zeroed w/ stats)
    int*   bbase  = bsum + 512;                               // NB+1 ints
    int*   gcur   = bbase + 512;                              // NB ints
    int*   bbase2 = gcur + 512;                               // NG+1 ints
    unsigned short* w1h = (unsigned short*)(bbase2 + 1024);
    unsigned short* w1l = w1h + 16384;
    unsigned short* w2h = w1l + 16384;
    unsigned short* w2l = w2h + 16384;
    int*   pairs2 = (int*)(w2l + 16384);                      // 2E ints = 12.8 MB

    float* out    = (float*)d_out;                            // h1 scratch + final out
    __half* xh    = (__half*)d_out;                           // fp16 mirror: d_out[0:25.6MB]
    int*   pairs1 = (int*)(out + (long long)N_NODES * (D / 2)); // d_out[25.6:38.4MB]

    {   // K0: fp16 convert + zero stats/bsum
        int grid = (N_NODES * (D / 4) + 255) / 256;
        convert_zero<<<grid, 256, 0, stream>>>(x, xh, (int*)stats);
    }
    {   // K1: bucket histogram
        int grid = (2 * EDGES + L1TILE - 1) / L1TILE;
        bucket_count<<<grid, 256, 0, stream>>>(ei, bsum);
    }
    {   // K2: scan bucket sums -> bbase, gcur
        scan_bsums<<<1, 512, 0, stream>>>(bsum, bbase, gcur);
    }
    {   // K2d: split W1/W2 -> bf16 hi/lo
        split_w<<<128, 256, 0, stream>>>(W1, W2, w1h, w1l, w2h, w2l);
    }
    {   // K3a: dst-bucket partition (packed pairs)
        int grid = (2 * EDGES + L1TILE - 1) / L1TILE;
        partition_pairs<<<grid, 256, 0, stream>>>(ei, gcur, pairs1);
    }
    {   // K3b: per-bucket counting sort by (half, src-bucket) -> pairs2, bbase2
        sort_pairs<<<NB, 512, 0, stream>>>(pairs1, bbase, pairs2, bbase2);
    }
    {   // K4: scatter-gather with native int LDS atomics -> hh/hl
        gather_scatter<<<NG, 512, 0, stream>>>(x, xh, pairs2, bbase2, eps_p, hh, hl);
    }
    {   // K5: MFMA GEMM1 + BN stats (h1 -> d_out)
        int grid = (N_NODES + TM - 1) / TM;
        gemm1_mfma<<<grid, 256, 0, stream>>>((const unsigned short*)hh, (const unsigned short*)hl,
                                             w1h, w1l, b1, out, stats);
    }
    {   // K6: BN finalize + ReLU + MFMA GEMM2, in-place on d_out
        int grid = (N_NODES + TM - 1) / TM;
        gemm2_mfma<<<grid, 256, 0, stream>>>(out, w2h, w2l, b2, stats, gamma, beta);
    }
}